// Round 12
// baseline (706.892 us; speedup 1.0000x reference)
//
#include <hip/hip_runtime.h>
#include <cstddef>

#define BN_EPS 1e-5f
constexpr int NNODES = 50000;
constexpr int NEDGES = 640000;
constexpr int DV = 128;
constexpr int NSLOT_E = 64;
constexpr int NSLOT_V = 64;

typedef __attribute__((ext_vector_type(4))) float f32x4;
typedef __attribute__((ext_vector_type(8))) short s16x8;
typedef unsigned short ushort_t;

__device__ __forceinline__ float lrelu(float x) { return x > 0.f ? x : 0.2f * x; }

// HW bf16 convert (RNE), gfx950 v_cvt_pk_bf16_f32
__device__ __forceinline__ unsigned cvt_pk_bf16(float lo, float hi) {
  unsigned r;
  asm("v_cvt_pk_bf16_f32 %0, %1, %2" : "=v"(r) : "v"(lo), "v"(hi));
  return r;
}
__device__ __forceinline__ ushort_t f2bf(float f) {
  unsigned r;
  asm("v_cvt_pk_bf16_f32 %0, %1, %1" : "=v"(r) : "v"(f));
  return (ushort_t)r;
}
__device__ __forceinline__ s16x8 pack8(float4 a, float4 b) {
  union { unsigned u[4]; s16x8 v; } r;
  r.u[0] = cvt_pk_bf16(a.x, a.y);
  r.u[1] = cvt_pk_bf16(a.z, a.w);
  r.u[2] = cvt_pk_bf16(b.x, b.y);
  r.u[3] = cvt_pk_bf16(b.z, b.w);
  return r.v;
}
__device__ __forceinline__ float bf2f(ushort_t u) {
  return __builtin_bit_cast(float, (unsigned int)u << 16);
}

// ---- fused prep: node f32->bf16 convert, idx1 histogram, weight pre-pack ----
// weight frag (kk,n): lane holds B[k = kk*32 + (lane>>4)*8 + j][col = n*16 + (lane&15)]
__global__ __launch_bounds__(256)
void prep(const float* __restrict__ node_fea, ushort_t* __restrict__ node_b,
          const int* __restrict__ idx1, int* __restrict__ deg,
          const float* __restrict__ W0, const float* __restrict__ W1,
          const float* __restrict__ W2, const float* __restrict__ W3,
          const float* __restrict__ W4, const float* __restrict__ W5,
          ushort_t* __restrict__ wpack) {
  int t = blockIdx.x * 256 + threadIdx.x;
  if (t < NNODES * DV / 8) {
    const float* s = node_fea + (size_t)t * 8;
    float4 x0 = *(const float4*)s;
    float4 x1 = *(const float4*)(s + 4);
    *(s16x8*)(node_b + (size_t)t * 8) = pack8(x0, x1);
  }
  if (t < NEDGES) atomicAdd(&deg[idx1[t]], 1);
  if (t < 288 * 64) {
    int lane = t & 63, f = t >> 6;
    const float* W; int lf;
    if (f < 96)       { W = W0; lf = f; }
    else if (f < 128) { W = W1; lf = f - 96; }
    else if (f < 160) { W = W2; lf = f - 128; }
    else if (f < 224) { W = W3; lf = f - 160; }
    else if (f < 256) { W = W4; lf = f - 224; }
    else              { W = W5; lf = f - 256; }
    int kk = lf >> 3, n = lf & 7;
    int k0 = kk * 32 + (lane >> 4) * 8, col = n * 16 + (lane & 15);
    s16x8 v;
#pragma unroll
    for (int j = 0; j < 8; j++) v[j] = (short)f2bf(W[(size_t)(k0 + j) * DV + col]);
    *(s16x8*)(wpack + (size_t)t * 8) = v;
  }
}

__global__ __launch_bounds__(256)
void csr_scan(const int* __restrict__ deg, int* __restrict__ row_ptr,
              int* __restrict__ cursor) {
  __shared__ int part[256];
  const int t = threadIdx.x;
  const int CH = (NNODES + 255) / 256;
  int s = 0;
  for (int i = 0; i < CH; i++) { int n = t * CH + i; if (n < NNODES) s += deg[n]; }
  part[t] = s;
  __syncthreads();
  if (t == 0) {
    int run = 0;
    for (int i = 0; i < 256; i++) { int v = part[i]; part[i] = run; run += v; }
  }
  __syncthreads();
  int run = part[t];
  for (int i = 0; i < CH; i++) {
    int n = t * CH + i;
    if (n < NNODES) { row_ptr[n] = run; cursor[n] = run; run += deg[n]; }
  }
}

__global__ __launch_bounds__(256)
void csr_fill(const int* __restrict__ idx1, int* __restrict__ cursor,
              int* __restrict__ eidx) {
  int e = blockIdx.x * 256 + threadIdx.x;
  if (e < NEDGES) {
    int pos = atomicAdd(&cursor[idx1[e]], 1);
    eidx[pos] = e;
  }
}

// ---- MFMA span: wave covers 32 rows (rg half) x 32 cols (nh quarter) of 64-row tile.
template<int RS>  // LDS row stride in bytes
__device__ __forceinline__ void mfma_span(const char* Als, const s16x8* __restrict__ Wp,
                                          int fkk0, int nkk, f32x4 acc[2][2],
                                          int lane, int rg, int nh) {
  const int col0 = lane & 15;
  const int kg16 = (lane >> 4) * 16;
  const int sw = (col0 & 7) << 4;
  const int r0 = (rg * 32 + col0) * RS;
  const int r1 = (rg * 32 + 16 + col0) * RS;
#pragma unroll
  for (int kk = 0; kk < nkk; kk++) {
    const int ko = (kk * 64 + kg16) ^ sw;
    s16x8 a0 = *(const s16x8*)(Als + r0 + ko);
    s16x8 a1 = *(const s16x8*)(Als + r1 + ko);
    s16x8 b0 = Wp[(size_t)((fkk0 + kk) * 8 + nh * 2 + 0) * 64 + lane];
    s16x8 b1 = Wp[(size_t)((fkk0 + kk) * 8 + nh * 2 + 1) * 64 + lane];
    acc[0][0] = __builtin_amdgcn_mfma_f32_16x16x32_bf16(a0, b0, acc[0][0], 0, 0, 0);
    acc[0][1] = __builtin_amdgcn_mfma_f32_16x16x32_bf16(a0, b1, acc[0][1], 0, 0, 0);
    acc[1][0] = __builtin_amdgcn_mfma_f32_16x16x32_bf16(a1, b0, acc[1][0], 0, 0, 0);
    acc[1][1] = __builtin_amdgcn_mfma_f32_16x16x32_bf16(a1, b1, acc[1][1], 0, 0, 0);
  }
}

// bias + lrelu + bf16 -> swizzled LDS (row stride 256B), 64-row tile shape
__device__ __forceinline__ void store_h64(char* H, const f32x4 acc[2][2],
                                          const float* __restrict__ bias,
                                          int lane, int rg, int nh) {
  const int col0 = lane & 15, lg = lane >> 4;
#pragma unroll
  for (int ar = 0; ar < 2; ar++) {
#pragma unroll
    for (int n = 0; n < 2; n++) {
      const int col = nh * 32 + n * 16 + col0;
      float bi = bias[col];
#pragma unroll
      for (int r = 0; r < 4; r++) {
        int row = rg * 32 + ar * 16 + lg * 4 + r;
        float v = lrelu(acc[ar][n][r] + bi);
        *(ushort_t*)(H + row * 256 + ((col * 2) ^ ((row & 7) << 4))) = f2bf(v);
      }
    }
  }
}

// h3 bf16 -> first 256B of each edge's 512B out_edge slot (ushort stride 256)
// BISECT NOTE: this is the round-9 kernel body verbatim; only the launch_bounds
// waves/EU hint changed 8 -> 6 (regalloc headroom for B-frag prefetch).
__global__ __launch_bounds__(512, 6)
void edge_mlp_mfma(const ushort_t* __restrict__ node_b, const float* __restrict__ edge_fea,
                   const int* __restrict__ idx1, const int* __restrict__ idx2,
                   const ushort_t* __restrict__ Wp1, const float* __restrict__ b1,
                   const ushort_t* __restrict__ Wp2, const float* __restrict__ b2,
                   const ushort_t* __restrict__ Wp3, const float* __restrict__ b3,
                   ushort_t* __restrict__ h3b, float* __restrict__ slots) {
  __shared__ __align__(16) char zsm[64 * 384];   // 24KB: z K-half, later h2
  __shared__ __align__(16) char hb[64 * 256];    // 16KB: h1, later BN partials
  const int tid = threadIdx.x;
  const int lane = tid & 63, wid = tid >> 6;
  const int rg = wid & 1, nh = wid >> 1;
  const int e0 = blockIdx.x * 64;

  // ---- gather K-half A: cols 0..191 = [node1 bf16 x16ch | node2 bf16 cols0-63 x8ch]
  for (int t = tid; t < 64 * 24; t += 512) {
    int e = t / 24, p = t % 24;
    int er = e0 + e;
    const ushort_t* src = (p < 16) ? (node_b + (size_t)idx1[er] * DV + p * 8)
                                   : (node_b + (size_t)idx2[er] * DV + (p - 16) * 8);
    s16x8 v = *(const s16x8*)src;
    *(s16x8*)(zsm + e * 384 + ((p * 16) ^ ((e & 7) << 4))) = v;
  }
  __syncthreads();

  f32x4 acc[2][2];
#pragma unroll
  for (int i = 0; i < 2; i++)
#pragma unroll
    for (int j = 0; j < 2; j++) acc[i][j] = 0.0f;

  // ---- layer 1, k = 0..191
  mfma_span<384>(zsm, (const s16x8*)Wp1, 0, 6, acc, lane, rg, nh);
  __syncthreads();   // all zsm reads done before overwrite

  // ---- gather K-half B: cols 192..383 = [node2 cols64-127 x8ch | edge f32 x16ch]
  for (int t = tid; t < 64 * 24; t += 512) {
    int e = t / 24, p = t % 24;
    int er = e0 + e;
    s16x8 v;
    if (p < 8) {
      v = *(const s16x8*)(node_b + (size_t)idx2[er] * DV + 64 + p * 8);
    } else {
      const float* s = edge_fea + (size_t)er * DV + (p - 8) * 8;
      float4 x0 = *(const float4*)s;
      float4 x1 = *(const float4*)(s + 4);
      v = pack8(x0, x1);
    }
    *(s16x8*)(zsm + e * 384 + ((p * 16) ^ ((e & 7) << 4))) = v;
  }
  __syncthreads();

  // ---- layer 1, k = 192..383 (frags 6..11)
  mfma_span<384>(zsm, (const s16x8*)Wp1, 6, 6, acc, lane, rg, nh);

  store_h64(hb, acc, b1, lane, rg, nh);
  __syncthreads();

  // ---- layer 2 (reads hb)
#pragma unroll
  for (int i = 0; i < 2; i++)
#pragma unroll
    for (int j = 0; j < 2; j++) acc[i][j] = 0.0f;
  mfma_span<256>(hb, (const s16x8*)Wp2, 0, 4, acc, lane, rg, nh);

  store_h64(zsm, acc, b2, lane, rg, nh);
  __syncthreads();

  // ---- layer 3 (reads zsm)
#pragma unroll
  for (int i = 0; i < 2; i++)
#pragma unroll
    for (int j = 0; j < 2; j++) acc[i][j] = 0.0f;
  mfma_span<256>(zsm, (const s16x8*)Wp3, 0, 4, acc, lane, rg, nh);

  // ---- epilogue: bias, bf16 h3 -> slot first half, BN partials (f32, exact)
  const int col0 = lane & 15, lg = lane >> 4;
  float* ps = (float*)hb;            // [16][128] 8KB
  float* pq = ps + 16 * DV;          // [16][128] 8KB
#pragma unroll
  for (int ar = 0; ar < 2; ar++) {
#pragma unroll
    for (int n = 0; n < 2; n++) {
      const int col = nh * 32 + n * 16 + col0;
      float bi = b3[col];
      float s = 0.f, q = 0.f;
#pragma unroll
      for (int r = 0; r < 4; r++) {
        int row = rg * 32 + ar * 16 + lg * 4 + r;
        float v = acc[ar][n][r] + bi;
        h3b[(size_t)(e0 + row) * 256 + col] = f2bf(v);
        s += v; q += v * v;
      }
      ps[(rg * 8 + ar * 4 + lg) * DV + col] = s;
      pq[(rg * 8 + ar * 4 + lg) * DV + col] = q;
    }
  }
  __syncthreads();
  if (tid < 128) {
    float s = 0.f, q = 0.f;
#pragma unroll
    for (int g = 0; g < 16; g++) { s += ps[g * DV + tid]; q += pq[g * DV + tid]; }
    float* sl = slots + (size_t)(blockIdx.x % NSLOT_E) * 256;
    atomicAdd(sl + tid, s);
    atomicAdd(sl + 128 + tid, q);
  }
}

// ---- fused per-node gather + edge finalize, half-wave split, 8-deep unroll ----
__global__ __launch_bounds__(256)
void node_gather_fused(const int* __restrict__ row_ptr, const int* __restrict__ deg,
                       const int* __restrict__ eidx, const float* __restrict__ edge_fea,
                       const float* __restrict__ ss, float* eslot,
                       ushort_t* __restrict__ vbar_b) {
  const int n = blockIdx.x * 4 + (threadIdx.x >> 6);
  const int lane = threadIdx.x & 63;
  if (n >= NNODES) return;
  const int half = lane >> 5;
  const int l = lane & 31;
  const int j = l * 4;                       // 4 cols per lane
  const int start = row_ptr[n], d = deg[n];
  const float4 sc = *(const float4*)(ss + j);
  const float4 sh = *(const float4*)(ss + 128 + j);
  const ushort_t* h3b = (const ushort_t*)eslot;
  float a0 = 0.f, a1 = 0.f, a2 = 0.f, a3 = 0.f;

#define PROC(ii)                                                              \
  {                                                                           \
    int e = eidx[start + (ii)];                                               \
    ushort4 u = *(const ushort4*)(h3b + (size_t)e * 256 + j);                 \
    float4 ef = *(const float4*)(edge_fea + (size_t)e * DV + j);              \
    float h0 = bf2f(u.x), h1 = bf2f(u.y), h2 = bf2f(u.z), h3v = bf2f(u.w);    \
    a0 += h0; a1 += h1; a2 += h2; a3 += h3v;                                  \
    float4 o;                                                                 \
    o.x = ef.x + fmaf(h0, sc.x, sh.x);                                        \
    o.y = ef.y + fmaf(h1, sc.y, sh.y);                                        \
    o.z = ef.z + fmaf(h2, sc.z, sh.z);                                        \
    o.w = ef.w + fmaf(h3v, sc.w, sh.w);                                       \
    *(float4*)(eslot + (size_t)e * DV + j) = o;                               \
  }

  int i = half;
  for (; i + 6 < d; i += 8) { PROC(i); PROC(i + 2); PROC(i + 4); PROC(i + 6); }
  for (; i + 2 < d; i += 4) { PROC(i); PROC(i + 2); }
  if (i < d) PROC(i);
#undef PROC

  // combine half-wave partials into lanes 0..31
  a0 += __shfl_down(a0, 32);
  a1 += __shfl_down(a1, 32);
  a2 += __shfl_down(a2, 32);
  a3 += __shfl_down(a3, 32);
  if (lane < 32) {
    float vx = 0.f, vy = 0.f, vz = 0.f, vw = 0.f;
    if (d > 0) {
      float inv = 1.f / (float)d;
      vx = fmaf(a0 * inv, sc.x, sh.x);
      vy = fmaf(a1 * inv, sc.y, sh.y);
      vz = fmaf(a2 * inv, sc.z, sh.z);
      vw = fmaf(a3 * inv, sc.w, sh.w);
    }
    unsigned p0 = cvt_pk_bf16(vx, vy);
    unsigned p1 = cvt_pk_bf16(vz, vw);
    uint2 vb = make_uint2(p0, p1);
    *(uint2*)(vbar_b + (size_t)n * DV + j) = vb;
  }
}

// ---- node MLP: 32-row tile, all-bf16 gather (pure copies) ----
template<int K>
__device__ __forceinline__ void layer_mfma(const char* Als, const s16x8* __restrict__ Wp,
                                           f32x4 acc[4], int lane, int rg, int nh) {
  const int arow = rg * 16 + (lane & 15);
  const int rowoff = arow * (K * 2);
  const int kg16 = (lane >> 4) * 16;
  const int sw = (arow & 7) << 4;
#pragma unroll
  for (int n = 0; n < 4; n++) acc[n] = 0.0f;
#pragma unroll 2
  for (int kk = 0; kk < K / 32; kk++) {
    s16x8 a = *(const s16x8*)(Als + rowoff + ((kk * 64 + kg16) ^ sw));
#pragma unroll
    for (int n = 0; n < 4; n++) {
      s16x8 b = Wp[(size_t)(kk * 8 + nh * 4 + n) * 64 + lane];
      acc[n] = __builtin_amdgcn_mfma_f32_16x16x32_bf16(a, b, acc[n], 0, 0, 0);
    }
  }
}

__device__ __forceinline__ void store_h_lds(char* H, const f32x4 acc[4],
                                            const float* __restrict__ bias,
                                            int lane, int rg, int nh) {
  const int col0 = lane & 15, lg = lane >> 4;
#pragma unroll
  for (int n = 0; n < 4; n++) {
    const int col = nh * 64 + n * 16 + col0;
    float bi = bias[col];
#pragma unroll
    for (int r = 0; r < 4; r++) {
      int row = rg * 16 + lg * 4 + r;
      float v = lrelu(acc[n][r] + bi);
      *(ushort_t*)(H + row * 256 + ((col * 2) ^ ((row & 7) << 4))) = f2bf(v);
    }
  }
}

__global__ __launch_bounds__(256)
void node_mlp_mfma(const ushort_t* __restrict__ node_b, const ushort_t* __restrict__ vbar_b,
                   const ushort_t* __restrict__ Wp1, const float* __restrict__ b1,
                   const ushort_t* __restrict__ Wp2, const float* __restrict__ b2,
                   const ushort_t* __restrict__ Wp3, const float* __restrict__ b3,
                   float* __restrict__ h_out, float* __restrict__ slots) {
  __shared__ __align__(16) char zsm[32 * 512];   // 16KB
  __shared__ __align__(16) char hb[32 * 256];    // 8KB: h1, later BN partials (ps+pq)
  const int tid = threadIdx.x;
  const int lane = tid & 63, wid = tid >> 6;
  const int rg = wid & 1, nh = wid >> 1;
  const int n0 = blockIdx.x * 32;

  for (int t = tid; t < 32 * 32; t += 256) {
    int e = t / 32, p = t % 32;
    int nr = n0 + e;
    s16x8 v = (s16x8)0;
    if (nr < NNODES) {
      const ushort_t* src = (p < 16) ? (vbar_b + (size_t)nr * DV + p * 8)
                                     : (node_b + (size_t)nr * DV + (p - 16) * 8);
      v = *(const s16x8*)src;
    }
    *(s16x8*)(zsm + e * 512 + ((p * 16) ^ ((e & 7) << 4))) = v;
  }
  __syncthreads();

  f32x4 acc[4];

  layer_mfma<256>(zsm, (const s16x8*)Wp1, acc, lane, rg, nh);
  store_h_lds(hb, acc, b1, lane, rg, nh);
  __syncthreads();

  layer_mfma<128>(hb, (const s16x8*)Wp2, acc, lane, rg, nh);
  __syncthreads();
  store_h_lds(zsm, acc, b2, lane, rg, nh);
  __syncthreads();

  layer_mfma<128>(zsm, (const s16x8*)Wp3, acc, lane, rg, nh);

  // pq moved from zsm to hb (latent WAR hazard removal): hb's last reader is
  // layer 2, two barriers upstream; zsm may still be read by other waves here.
  const int col0 = lane & 15, lg = lane >> 4;
  float* ps = (float*)hb;            // [8][128] 4KB
  float* pq = ps + 8 * DV;           // [8][128] 4KB
#pragma unroll
  for (int n = 0; n < 4; n++) {
    const int col = nh * 64 + n * 16 + col0;
    float bi = b3[col];
    float s = 0.f, q = 0.f;
#pragma unroll
    for (int r = 0; r < 4; r++) {
      int row = rg * 16 + lg * 4 + r;
      int gr = n0 + row;
      if (gr < NNODES) {
        float v = acc[n][r] + bi;
        h_out[(size_t)gr * DV + col] = v;
        s += v; q += v * v;
      }
    }
    ps[(rg * 4 + lg) * DV + col] = s;
    pq[(rg * 4 + lg) * DV + col] = q;
  }
  __syncthreads();
  if (tid < 128) {
    float s = 0.f, q = 0.f;
#pragma unroll
    for (int g = 0; g < 8; g++) { s += ps[g * DV + tid]; q += pq[g * DV + tid]; }
    float* sl = slots + (size_t)(blockIdx.x % NSLOT_V) * 256;
    atomicAdd(sl + tid, s);
    atomicAdd(sl + 128 + tid, q);
  }
}

__global__ __launch_bounds__(256)
void stats_reduce(const float* __restrict__ slots, int nslot, float inv_n,
                  const float* __restrict__ gamma, const float* __restrict__ beta,
                  float* __restrict__ ss) {
  __shared__ float tot[256];
  const int j = threadIdx.x;
  float s = 0.f;
  for (int t = 0; t < nslot; t++) s += slots[(size_t)t * 256 + j];
  tot[j] = s;
  __syncthreads();
  if (j < 128) {
    float mean = tot[j] * inv_n;
    float var = tot[j + 128] * inv_n - mean * mean;
    float rs = rsqrtf(var + BN_EPS);
    float sc = gamma[j] * rs;
    ss[j] = sc;
    ss[128 + j] = beta[j] - mean * sc;
  }
}

__global__ __launch_bounds__(256)
void node_finalize(const float* __restrict__ node_fea, const float* __restrict__ ss,
                   float* __restrict__ h_inout) {
  const size_t base = (size_t)blockIdx.x * 1024 + threadIdx.x * 4;
  const int j = (int)(base & 127);
  float4 h = *(float4*)&h_inout[base];
  float4 nf = *(const float4*)&node_fea[base];
  float4 o;
  o.x = nf.x + fmaf(h.x, ss[j + 0], ss[128 + j + 0]);
  o.y = nf.y + fmaf(h.y, ss[j + 1], ss[128 + j + 1]);
  o.z = nf.z + fmaf(h.z, ss[j + 2], ss[128 + j + 2]);
  o.w = nf.w + fmaf(h.w, ss[j + 3], ss[128 + j + 3]);
  *(float4*)&h_inout[base] = o;
}

extern "C" void kernel_launch(void* const* d_in, const int* in_sizes, int n_in,
                              void* d_out, int out_size, void* d_ws, size_t ws_size,
                              hipStream_t stream) {
  const float* node_fea = (const float*)d_in[0];
  const float* edge_fea = (const float*)d_in[1];
  const int* idx1 = (const int*)d_in[2];
  const int* idx2 = (const int*)d_in[3];
  const float* We1 = (const float*)d_in[4];  const float* be1 = (const float*)d_in[5];
  const float* We2 = (const float*)d_in[6];  const float* be2 = (const float*)d_in[7];
  const float* We3 = (const float*)d_in[8];  const float* be3 = (const float*)d_in[9];
  const float* Wv1 = (const float*)d_in[10]; const float* bv1 = (const float*)d_in[11];
  const float* Wv2 = (const float*)d_in[12]; const float* bv2 = (const float*)d_in[13];
  const float* Wv3 = (const float*)d_in[14]; const float* bv3 = (const float*)d_in[15];
  const float* gamma_e = (const float*)d_in[16]; const float* beta_e = (const float*)d_in[17];
  const float* gamma_v = (const float*)d_in[18]; const float* beta_v = (const float*)d_in[19];

  float* out_node = (float*)d_out;                     // [NNODES][128]
  float* out_edge = out_node + (size_t)NNODES * DV;    // [NEDGES][128] (also bf16 h3 slots)

  float* ws = (float*)d_ws;
  size_t o = 0;
  // zeroed region first: deg + BN slots
  int* deg = (int*)(ws + o);      o += NNODES;
  float* slots_e = ws + o;        o += (size_t)NSLOT_E * 256;
  float* slots_v = ws + o;        o += (size_t)NSLOT_V * 256;
  const size_t zero_bytes = o * sizeof(float);
  // non-zeroed scratch
  int* row_ptr = (int*)(ws + o);  o += NNODES;
  int* cursor = (int*)(ws + o);   o += NNODES;
  int* eidx = (int*)(ws + o);     o += NEDGES;
  float* ss_e = ws + o;           o += 256;
  float* ss_v = ws + o;           o += 256;
  ushort_t* node_b = (ushort_t*)(ws + o);  o += (size_t)NNODES * DV / 2;  // bf16 nodes
  ushort_t* vbar_b = (ushort_t*)(ws + o);  o += (size_t)NNODES * DV / 2;  // bf16 vbar
  ushort_t* wpack = (ushort_t*)(ws + o);   // 288 frags * 512 ushort = 288KB

  const ushort_t* Wp_e1 = wpack;
  const ushort_t* Wp_e2 = wpack + (size_t)96 * 512;
  const ushort_t* Wp_e3 = wpack + (size_t)128 * 512;
  const ushort_t* Wp_v1 = wpack + (size_t)160 * 512;
  const ushort_t* Wp_v2 = wpack + (size_t)224 * 512;
  const ushort_t* Wp_v3 = wpack + (size_t)256 * 512;

  hipMemsetAsync(d_ws, 0, zero_bytes, stream);

  prep<<<(NNODES * DV / 8 + 255) / 256, 256, 0, stream>>>(
      node_fea, node_b, idx1, deg, We1, We2, We3, Wv1, Wv2, Wv3, wpack);
  csr_scan<<<1, 256, 0, stream>>>(deg, row_ptr, cursor);
  csr_fill<<<(NEDGES + 255) / 256, 256, 0, stream>>>(idx1, cursor, eidx);

  edge_mlp_mfma<<<NEDGES / 64, 512, 0, stream>>>(node_b, edge_fea, idx1, idx2,
                                                 Wp_e1, be1, Wp_e2, be2, Wp_e3, be3,
                                                 (ushort_t*)out_edge, slots_e);
  stats_reduce<<<1, 256, 0, stream>>>(slots_e, NSLOT_E, 1.f / NEDGES, gamma_e, beta_e, ss_e);
  node_gather_fused<<<(NNODES + 3) / 4, 256, 0, stream>>>(row_ptr, deg, eidx, edge_fea,
                                                          ss_e, out_edge, vbar_b);
  node_mlp_mfma<<<(NNODES + 31) / 32, 256, 0, stream>>>(node_b, vbar_b,
                                                        Wp_v1, bv1, Wp_v2, bv2, Wp_v3, bv3,
                                                        out_node, slots_v);
  stats_reduce<<<1, 256, 0, stream>>>(slots_v, NSLOT_V, 1.f / NNODES, gamma_v, beta_v, ss_v);
  node_finalize<<<(NNODES * DV) / 1024, 256, 0, stream>>>(node_fea, ss_v, out_node);
}

// Round 13
// 696.938 us; speedup vs baseline: 1.0143x; 1.0143x over previous
//
#include <hip/hip_runtime.h>
#include <cstddef>

#define BN_EPS 1e-5f
constexpr int NNODES = 50000;
constexpr int NEDGES = 640000;
constexpr int DV = 128;
constexpr int NSLOT_E = 64;
constexpr int NSLOT_V = 64;

typedef __attribute__((ext_vector_type(4))) float f32x4;
typedef __attribute__((ext_vector_type(8))) short s16x8;
typedef unsigned short ushort_t;

__device__ __forceinline__ float lrelu(float x) { return x > 0.f ? x : 0.2f * x; }

// HW bf16 convert (RNE), gfx950 v_cvt_pk_bf16_f32
__device__ __forceinline__ unsigned cvt_pk_bf16(float lo, float hi) {
  unsigned r;
  asm("v_cvt_pk_bf16_f32 %0, %1, %2" : "=v"(r) : "v"(lo), "v"(hi));
  return r;
}
__device__ __forceinline__ ushort_t f2bf(float f) {
  unsigned r;
  asm("v_cvt_pk_bf16_f32 %0, %1, %1" : "=v"(r) : "v"(f));
  return (ushort_t)r;
}
__device__ __forceinline__ s16x8 pack8(float4 a, float4 b) {
  union { unsigned u[4]; s16x8 v; } r;
  r.u[0] = cvt_pk_bf16(a.x, a.y);
  r.u[1] = cvt_pk_bf16(a.z, a.w);
  r.u[2] = cvt_pk_bf16(b.x, b.y);
  r.u[3] = cvt_pk_bf16(b.z, b.w);
  return r.v;
}
__device__ __forceinline__ float bf2f(ushort_t u) {
  return __builtin_bit_cast(float, (unsigned int)u << 16);
}

// ---- fused prep: node f32->bf16 convert, idx1 histogram, weight pre-pack ----
// weight frag (kk,n): lane holds B[k = kk*32 + (lane>>4)*8 + j][col = n*16 + (lane&15)]
__global__ __launch_bounds__(256)
void prep(const float* __restrict__ node_fea, ushort_t* __restrict__ node_b,
          const int* __restrict__ idx1, int* __restrict__ deg,
          const float* __restrict__ W0, const float* __restrict__ W1,
          const float* __restrict__ W2, const float* __restrict__ W3,
          const float* __restrict__ W4, const float* __restrict__ W5,
          ushort_t* __restrict__ wpack) {
  int t = blockIdx.x * 256 + threadIdx.x;
  if (t < NNODES * DV / 8) {
    const float* s = node_fea + (size_t)t * 8;
    float4 x0 = *(const float4*)s;
    float4 x1 = *(const float4*)(s + 4);
    *(s16x8*)(node_b + (size_t)t * 8) = pack8(x0, x1);
  }
  if (t < NEDGES) atomicAdd(&deg[idx1[t]], 1);
  if (t < 288 * 64) {
    int lane = t & 63, f = t >> 6;
    const float* W; int lf;
    if (f < 96)       { W = W0; lf = f; }
    else if (f < 128) { W = W1; lf = f - 96; }
    else if (f < 160) { W = W2; lf = f - 128; }
    else if (f < 224) { W = W3; lf = f - 160; }
    else if (f < 256) { W = W4; lf = f - 224; }
    else              { W = W5; lf = f - 256; }
    int kk = lf >> 3, n = lf & 7;
    int k0 = kk * 32 + (lane >> 4) * 8, col = n * 16 + (lane & 15);
    s16x8 v;
#pragma unroll
    for (int j = 0; j < 8; j++) v[j] = (short)f2bf(W[(size_t)(k0 + j) * DV + col]);
    *(s16x8*)(wpack + (size_t)t * 8) = v;
  }
}

__global__ __launch_bounds__(256)
void csr_scan(const int* __restrict__ deg, int* __restrict__ row_ptr,
              int* __restrict__ cursor) {
  __shared__ int part[256];
  const int t = threadIdx.x;
  const int CH = (NNODES + 255) / 256;
  int s = 0;
  for (int i = 0; i < CH; i++) { int n = t * CH + i; if (n < NNODES) s += deg[n]; }
  part[t] = s;
  __syncthreads();
  if (t == 0) {
    int run = 0;
    for (int i = 0; i < 256; i++) { int v = part[i]; part[i] = run; run += v; }
  }
  __syncthreads();
  int run = part[t];
  for (int i = 0; i < CH; i++) {
    int n = t * CH + i;
    if (n < NNODES) { row_ptr[n] = run; cursor[n] = run; run += deg[n]; }
  }
}

__global__ __launch_bounds__(256)
void csr_fill(const int* __restrict__ idx1, int* __restrict__ cursor,
              int* __restrict__ eidx) {
  int e = blockIdx.x * 256 + threadIdx.x;
  if (e < NEDGES) {
    int pos = atomicAdd(&cursor[idx1[e]], 1);
    eidx[pos] = e;
  }
}

// ---- MFMA span: wave covers 32 rows (rg half) x 32 cols (nh quarter) of 64-row tile.
// B-fragment SOFTWARE PREFETCH: kk+1's two 1KB frags are loaded while kk's MFMAs
// run (register double-buffer; fully unrolled so all indices are static).
template<int RS>  // LDS row stride in bytes
__device__ __forceinline__ void mfma_span(const char* Als, const s16x8* __restrict__ Wp,
                                          int fkk0, int nkk, f32x4 acc[2][2],
                                          int lane, int rg, int nh) {
  const int col0 = lane & 15;
  const int kg16 = (lane >> 4) * 16;
  const int sw = (col0 & 7) << 4;
  const int r0 = (rg * 32 + col0) * RS;
  const int r1 = (rg * 32 + 16 + col0) * RS;
  const s16x8* wp = Wp + (size_t)(fkk0 * 8 + nh * 2) * 64 + lane;  // frag row stride 512
  s16x8 b0 = wp[0];
  s16x8 b1 = wp[64];
#pragma unroll
  for (int kk = 0; kk < nkk; kk++) {
    s16x8 nb0, nb1;
    if (kk + 1 < nkk) {
      nb0 = wp[(kk + 1) * 512];
      nb1 = wp[(kk + 1) * 512 + 64];
    }
    const int ko = (kk * 64 + kg16) ^ sw;
    s16x8 a0 = *(const s16x8*)(Als + r0 + ko);
    s16x8 a1 = *(const s16x8*)(Als + r1 + ko);
    acc[0][0] = __builtin_amdgcn_mfma_f32_16x16x32_bf16(a0, b0, acc[0][0], 0, 0, 0);
    acc[0][1] = __builtin_amdgcn_mfma_f32_16x16x32_bf16(a0, b1, acc[0][1], 0, 0, 0);
    acc[1][0] = __builtin_amdgcn_mfma_f32_16x16x32_bf16(a1, b0, acc[1][0], 0, 0, 0);
    acc[1][1] = __builtin_amdgcn_mfma_f32_16x16x32_bf16(a1, b1, acc[1][1], 0, 0, 0);
    b0 = nb0;
    b1 = nb1;
  }
}

// bias + lrelu + bf16 -> swizzled LDS (row stride 256B), 64-row tile shape
__device__ __forceinline__ void store_h64(char* H, const f32x4 acc[2][2],
                                          const float* __restrict__ bias,
                                          int lane, int rg, int nh) {
  const int col0 = lane & 15, lg = lane >> 4;
#pragma unroll
  for (int ar = 0; ar < 2; ar++) {
#pragma unroll
    for (int n = 0; n < 2; n++) {
      const int col = nh * 32 + n * 16 + col0;
      float bi = bias[col];
#pragma unroll
      for (int r = 0; r < 4; r++) {
        int row = rg * 32 + ar * 16 + lg * 4 + r;
        float v = lrelu(acc[ar][n][r] + bi);
        *(ushort_t*)(H + row * 256 + ((col * 2) ^ ((row & 7) << 4))) = f2bf(v);
      }
    }
  }
}

// h3 bf16 -> first 256B of each edge's 512B out_edge slot (ushort stride 256)
// launch_bounds back to (512,8): R12's (512,6) cost occupancy (87->65%) for nothing.
__global__ __launch_bounds__(512, 8)
void edge_mlp_mfma(const ushort_t* __restrict__ node_b, const float* __restrict__ edge_fea,
                   const int* __restrict__ idx1, const int* __restrict__ idx2,
                   const ushort_t* __restrict__ Wp1, const float* __restrict__ b1,
                   const ushort_t* __restrict__ Wp2, const float* __restrict__ b2,
                   const ushort_t* __restrict__ Wp3, const float* __restrict__ b3,
                   ushort_t* __restrict__ h3b, float* __restrict__ slots) {
  __shared__ __align__(16) char zsm[64 * 384];   // 24KB: z K-half, later h2
  __shared__ __align__(16) char hb[64 * 256];    // 16KB: h1, later BN partials
  const int tid = threadIdx.x;
  const int lane = tid & 63, wid = tid >> 6;
  const int rg = wid & 1, nh = wid >> 1;
  const int e0 = blockIdx.x * 64;

  // ---- gather K-half A: cols 0..191 = [node1 bf16 x16ch | node2 bf16 cols0-63 x8ch]
  for (int t = tid; t < 64 * 24; t += 512) {
    int e = t / 24, p = t % 24;
    int er = e0 + e;
    const ushort_t* src = (p < 16) ? (node_b + (size_t)idx1[er] * DV + p * 8)
                                   : (node_b + (size_t)idx2[er] * DV + (p - 16) * 8);
    s16x8 v = *(const s16x8*)src;
    *(s16x8*)(zsm + e * 384 + ((p * 16) ^ ((e & 7) << 4))) = v;
  }
  __syncthreads();

  f32x4 acc[2][2];
#pragma unroll
  for (int i = 0; i < 2; i++)
#pragma unroll
    for (int j = 0; j < 2; j++) acc[i][j] = 0.0f;

  // ---- layer 1, k = 0..191
  mfma_span<384>(zsm, (const s16x8*)Wp1, 0, 6, acc, lane, rg, nh);
  __syncthreads();   // all zsm reads done before overwrite

  // ---- gather K-half B: cols 192..383 = [node2 cols64-127 x8ch | edge f32 x16ch]
  for (int t = tid; t < 64 * 24; t += 512) {
    int e = t / 24, p = t % 24;
    int er = e0 + e;
    s16x8 v;
    if (p < 8) {
      v = *(const s16x8*)(node_b + (size_t)idx2[er] * DV + 64 + p * 8);
    } else {
      const float* s = edge_fea + (size_t)er * DV + (p - 8) * 8;
      float4 x0 = *(const float4*)s;
      float4 x1 = *(const float4*)(s + 4);
      v = pack8(x0, x1);
    }
    *(s16x8*)(zsm + e * 384 + ((p * 16) ^ ((e & 7) << 4))) = v;
  }
  __syncthreads();

  // ---- layer 1, k = 192..383 (frags 6..11)
  mfma_span<384>(zsm, (const s16x8*)Wp1, 6, 6, acc, lane, rg, nh);

  store_h64(hb, acc, b1, lane, rg, nh);
  __syncthreads();

  // ---- layer 2 (reads hb)
#pragma unroll
  for (int i = 0; i < 2; i++)
#pragma unroll
    for (int j = 0; j < 2; j++) acc[i][j] = 0.0f;
  mfma_span<256>(hb, (const s16x8*)Wp2, 0, 4, acc, lane, rg, nh);

  store_h64(zsm, acc, b2, lane, rg, nh);
  __syncthreads();

  // ---- layer 3 (reads zsm)
#pragma unroll
  for (int i = 0; i < 2; i++)
#pragma unroll
    for (int j = 0; j < 2; j++) acc[i][j] = 0.0f;
  mfma_span<256>(zsm, (const s16x8*)Wp3, 0, 4, acc, lane, rg, nh);

  // ---- epilogue: bias, bf16 h3 -> slot first half, BN partials (f32, exact)
  const int col0 = lane & 15, lg = lane >> 4;
  float* ps = (float*)hb;            // [16][128] 8KB
  float* pq = ps + 16 * DV;          // [16][128] 8KB
#pragma unroll
  for (int ar = 0; ar < 2; ar++) {
#pragma unroll
    for (int n = 0; n < 2; n++) {
      const int col = nh * 32 + n * 16 + col0;
      float bi = b3[col];
      float s = 0.f, q = 0.f;
#pragma unroll
      for (int r = 0; r < 4; r++) {
        int row = rg * 32 + ar * 16 + lg * 4 + r;
        float v = acc[ar][n][r] + bi;
        h3b[(size_t)(e0 + row) * 256 + col] = f2bf(v);
        s += v; q += v * v;
      }
      ps[(rg * 8 + ar * 4 + lg) * DV + col] = s;
      pq[(rg * 8 + ar * 4 + lg) * DV + col] = q;
    }
  }
  __syncthreads();
  if (tid < 128) {
    float s = 0.f, q = 0.f;
#pragma unroll
    for (int g = 0; g < 16; g++) { s += ps[g * DV + tid]; q += pq[g * DV + tid]; }
    float* sl = slots + (size_t)(blockIdx.x % NSLOT_E) * 256;
    atomicAdd(sl + tid, s);
    atomicAdd(sl + 128 + tid, q);
  }
}

// ---- fused per-node gather + edge finalize, half-wave split, 8-deep unroll ----
__global__ __launch_bounds__(256)
void node_gather_fused(const int* __restrict__ row_ptr, const int* __restrict__ deg,
                       const int* __restrict__ eidx, const float* __restrict__ edge_fea,
                       const float* __restrict__ ss, float* eslot,
                       ushort_t* __restrict__ vbar_b) {
  const int n = blockIdx.x * 4 + (threadIdx.x >> 6);
  const int lane = threadIdx.x & 63;
  if (n >= NNODES) return;
  const int half = lane >> 5;
  const int l = lane & 31;
  const int j = l * 4;                       // 4 cols per lane
  const int start = row_ptr[n], d = deg[n];
  const float4 sc = *(const float4*)(ss + j);
  const float4 sh = *(const float4*)(ss + 128 + j);
  const ushort_t* h3b = (const ushort_t*)eslot;
  float a0 = 0.f, a1 = 0.f, a2 = 0.f, a3 = 0.f;

#define PROC(ii)                                                              \
  {                                                                           \
    int e = eidx[start + (ii)];                                               \
    ushort4 u = *(const ushort4*)(h3b + (size_t)e * 256 + j);                 \
    float4 ef = *(const float4*)(edge_fea + (size_t)e * DV + j);              \
    float h0 = bf2f(u.x), h1 = bf2f(u.y), h2 = bf2f(u.z), h3v = bf2f(u.w);    \
    a0 += h0; a1 += h1; a2 += h2; a3 += h3v;                                  \
    float4 o;                                                                 \
    o.x = ef.x + fmaf(h0, sc.x, sh.x);                                        \
    o.y = ef.y + fmaf(h1, sc.y, sh.y);                                        \
    o.z = ef.z + fmaf(h2, sc.z, sh.z);                                        \
    o.w = ef.w + fmaf(h3v, sc.w, sh.w);                                       \
    *(float4*)(eslot + (size_t)e * DV + j) = o;                               \
  }

  int i = half;
  for (; i + 6 < d; i += 8) { PROC(i); PROC(i + 2); PROC(i + 4); PROC(i + 6); }
  for (; i + 2 < d; i += 4) { PROC(i); PROC(i + 2); }
  if (i < d) PROC(i);
#undef PROC

  // combine half-wave partials into lanes 0..31
  a0 += __shfl_down(a0, 32);
  a1 += __shfl_down(a1, 32);
  a2 += __shfl_down(a2, 32);
  a3 += __shfl_down(a3, 32);
  if (lane < 32) {
    float vx = 0.f, vy = 0.f, vz = 0.f, vw = 0.f;
    if (d > 0) {
      float inv = 1.f / (float)d;
      vx = fmaf(a0 * inv, sc.x, sh.x);
      vy = fmaf(a1 * inv, sc.y, sh.y);
      vz = fmaf(a2 * inv, sc.z, sh.z);
      vw = fmaf(a3 * inv, sc.w, sh.w);
    }
    unsigned p0 = cvt_pk_bf16(vx, vy);
    unsigned p1 = cvt_pk_bf16(vz, vw);
    uint2 vb = make_uint2(p0, p1);
    *(uint2*)(vbar_b + (size_t)n * DV + j) = vb;
  }
}

// ---- node MLP: 32-row tile, all-bf16 gather (pure copies) ----
template<int K>
__device__ __forceinline__ void layer_mfma(const char* Als, const s16x8* __restrict__ Wp,
                                           f32x4 acc[4], int lane, int rg, int nh) {
  const int arow = rg * 16 + (lane & 15);
  const int rowoff = arow * (K * 2);
  const int kg16 = (lane >> 4) * 16;
  const int sw = (arow & 7) << 4;
#pragma unroll
  for (int n = 0; n < 4; n++) acc[n] = 0.0f;
#pragma unroll 2
  for (int kk = 0; kk < K / 32; kk++) {
    s16x8 a = *(const s16x8*)(Als + rowoff + ((kk * 64 + kg16) ^ sw));
#pragma unroll
    for (int n = 0; n < 4; n++) {
      s16x8 b = Wp[(size_t)(kk * 8 + nh * 4 + n) * 64 + lane];
      acc[n] = __builtin_amdgcn_mfma_f32_16x16x32_bf16(a, b, acc[n], 0, 0, 0);
    }
  }
}

__device__ __forceinline__ void store_h_lds(char* H, const f32x4 acc[4],
                                            const float* __restrict__ bias,
                                            int lane, int rg, int nh) {
  const int col0 = lane & 15, lg = lane >> 4;
#pragma unroll
  for (int n = 0; n < 4; n++) {
    const int col = nh * 64 + n * 16 + col0;
    float bi = bias[col];
#pragma unroll
    for (int r = 0; r < 4; r++) {
      int row = rg * 16 + lg * 4 + r;
      float v = lrelu(acc[n][r] + bi);
      *(ushort_t*)(H + row * 256 + ((col * 2) ^ ((row & 7) << 4))) = f2bf(v);
    }
  }
}

__global__ __launch_bounds__(256)
void node_mlp_mfma(const ushort_t* __restrict__ node_b, const ushort_t* __restrict__ vbar_b,
                   const ushort_t* __restrict__ Wp1, const float* __restrict__ b1,
                   const ushort_t* __restrict__ Wp2, const float* __restrict__ b2,
                   const ushort_t* __restrict__ Wp3, const float* __restrict__ b3,
                   float* __restrict__ h_out, float* __restrict__ slots) {
  __shared__ __align__(16) char zsm[32 * 512];   // 16KB
  __shared__ __align__(16) char hb[32 * 256];    // 8KB: h1, later BN partials (ps+pq)
  const int tid = threadIdx.x;
  const int lane = tid & 63, wid = tid >> 6;
  const int rg = wid & 1, nh = wid >> 1;
  const int n0 = blockIdx.x * 32;

  for (int t = tid; t < 32 * 32; t += 256) {
    int e = t / 32, p = t % 32;
    int nr = n0 + e;
    s16x8 v = (s16x8)0;
    if (nr < NNODES) {
      const ushort_t* src = (p < 16) ? (vbar_b + (size_t)nr * DV + p * 8)
                                     : (node_b + (size_t)nr * DV + (p - 16) * 8);
      v = *(const s16x8*)src;
    }
    *(s16x8*)(zsm + e * 512 + ((p * 16) ^ ((e & 7) << 4))) = v;
  }
  __syncthreads();

  f32x4 acc[4];

  layer_mfma<256>(zsm, (const s16x8*)Wp1, acc, lane, rg, nh);
  store_h_lds(hb, acc, b1, lane, rg, nh);
  __syncthreads();

  layer_mfma<128>(hb, (const s16x8*)Wp2, acc, lane, rg, nh);
  __syncthreads();
  store_h_lds(zsm, acc, b2, lane, rg, nh);
  __syncthreads();

  layer_mfma<128>(zsm, (const s16x8*)Wp3, acc, lane, rg, nh);

  // pq in hb (not zsm): zsm may still be read by other waves' layer-3 A frags.
  const int col0 = lane & 15, lg = lane >> 4;
  float* ps = (float*)hb;            // [8][128] 4KB
  float* pq = ps + 8 * DV;           // [8][128] 4KB
#pragma unroll
  for (int n = 0; n < 4; n++) {
    const int col = nh * 64 + n * 16 + col0;
    float bi = b3[col];
    float s = 0.f, q = 0.f;
#pragma unroll
    for (int r = 0; r < 4; r++) {
      int row = rg * 16 + lg * 4 + r;
      int gr = n0 + row;
      if (gr < NNODES) {
        float v = acc[n][r] + bi;
        h_out[(size_t)gr * DV + col] = v;
        s += v; q += v * v;
      }
    }
    ps[(rg * 4 + lg) * DV + col] = s;
    pq[(rg * 4 + lg) * DV + col] = q;
  }
  __syncthreads();
  if (tid < 128) {
    float s = 0.f, q = 0.f;
#pragma unroll
    for (int g = 0; g < 8; g++) { s += ps[g * DV + tid]; q += pq[g * DV + tid]; }
    float* sl = slots + (size_t)(blockIdx.x % NSLOT_V) * 256;
    atomicAdd(sl + tid, s);
    atomicAdd(sl + 128 + tid, q);
  }
}

__global__ __launch_bounds__(256)
void stats_reduce(const float* __restrict__ slots, int nslot, float inv_n,
                  const float* __restrict__ gamma, const float* __restrict__ beta,
                  float* __restrict__ ss) {
  __shared__ float tot[256];
  const int j = threadIdx.x;
  float s = 0.f;
  for (int t = 0; t < nslot; t++) s += slots[(size_t)t * 256 + j];
  tot[j] = s;
  __syncthreads();
  if (j < 128) {
    float mean = tot[j] * inv_n;
    float var = tot[j + 128] * inv_n - mean * mean;
    float rs = rsqrtf(var + BN_EPS);
    float sc = gamma[j] * rs;
    ss[j] = sc;
    ss[128 + j] = beta[j] - mean * sc;
  }
}

__global__ __launch_bounds__(256)
void node_finalize(const float* __restrict__ node_fea, const float* __restrict__ ss,
                   float* __restrict__ h_inout) {
  const size_t base = (size_t)blockIdx.x * 1024 + threadIdx.x * 4;
  const int j = (int)(base & 127);
  float4 h = *(float4*)&h_inout[base];
  float4 nf = *(const float4*)&node_fea[base];
  float4 o;
  o.x = nf.x + fmaf(h.x, ss[j + 0], ss[128 + j + 0]);
  o.y = nf.y + fmaf(h.y, ss[j + 1], ss[128 + j + 1]);
  o.z = nf.z + fmaf(h.z, ss[j + 2], ss[128 + j + 2]);
  o.w = nf.w + fmaf(h.w, ss[j + 3], ss[128 + j + 3]);
  *(float4*)&h_inout[base] = o;
}

extern "C" void kernel_launch(void* const* d_in, const int* in_sizes, int n_in,
                              void* d_out, int out_size, void* d_ws, size_t ws_size,
                              hipStream_t stream) {
  const float* node_fea = (const float*)d_in[0];
  const float* edge_fea = (const float*)d_in[1];
  const int* idx1 = (const int*)d_in[2];
  const int* idx2 = (const int*)d_in[3];
  const float* We1 = (const float*)d_in[4];  const float* be1 = (const float*)d_in[5];
  const float* We2 = (const float*)d_in[6];  const float* be2 = (const float*)d_in[7];
  const float* We3 = (const float*)d_in[8];  const float* be3 = (const float*)d_in[9];
  const float* Wv1 = (const float*)d_in[10]; const float* bv1 = (const float*)d_in[11];
  const float* Wv2 = (const float*)d_in[12]; const float* bv2 = (const float*)d_in[13];
  const float* Wv3 = (const float*)d_in[14]; const float* bv3 = (const float*)d_in[15];
  const float* gamma_e = (const float*)d_in[16]; const float* beta_e = (const float*)d_in[17];
  const float* gamma_v = (const float*)d_in[18]; const float* beta_v = (const float*)d_in[19];

  float* out_node = (float*)d_out;                     // [NNODES][128]
  float* out_edge = out_node + (size_t)NNODES * DV;    // [NEDGES][128] (also bf16 h3 slots)

  float* ws = (float*)d_ws;
  size_t o = 0;
  // zeroed region first: deg + BN slots
  int* deg = (int*)(ws + o);      o += NNODES;
  float* slots_e = ws + o;        o += (size_t)NSLOT_E * 256;
  float* slots_v = ws + o;        o += (size_t)NSLOT_V * 256;
  const size_t zero_bytes = o * sizeof(float);
  // non-zeroed scratch
  int* row_ptr = (int*)(ws + o);  o += NNODES;
  int* cursor = (int*)(ws + o);   o += NNODES;
  int* eidx = (int*)(ws + o);     o += NEDGES;
  float* ss_e = ws + o;           o += 256;
  float* ss_v = ws + o;           o += 256;
  ushort_t* node_b = (ushort_t*)(ws + o);  o += (size_t)NNODES * DV / 2;  // bf16 nodes
  ushort_t* vbar_b = (ushort_t*)(ws + o);  o += (size_t)NNODES * DV / 2;  // bf16 vbar
  ushort_t* wpack = (ushort_t*)(ws + o);   // 288 frags * 512 ushort = 288KB

  const ushort_t* Wp_e1 = wpack;
  const ushort_t* Wp_e2 = wpack + (size_t)96 * 512;
  const ushort_t* Wp_e3 = wpack + (size_t)128 * 512;
  const ushort_t* Wp_v1 = wpack + (size_t)160 * 512;
  const ushort_t* Wp_v2 = wpack + (size_t)224 * 512;
  const ushort_t* Wp_v3 = wpack + (size_t)256 * 512;

  hipMemsetAsync(d_ws, 0, zero_bytes, stream);

  prep<<<(NNODES * DV / 8 + 255) / 256, 256, 0, stream>>>(
      node_fea, node_b, idx1, deg, We1, We2, We3, Wv1, Wv2, Wv3, wpack);
  csr_scan<<<1, 256, 0, stream>>>(deg, row_ptr, cursor);
  csr_fill<<<(NEDGES + 255) / 256, 256, 0, stream>>>(idx1, cursor, eidx);

  edge_mlp_mfma<<<NEDGES / 64, 512, 0, stream>>>(node_b, edge_fea, idx1, idx2,
                                                 Wp_e1, be1, Wp_e2, be2, Wp_e3, be3,
                                                 (ushort_t*)out_edge, slots_e);
  stats_reduce<<<1, 256, 0, stream>>>(slots_e, NSLOT_E, 1.f / NEDGES, gamma_e, beta_e, ss_e);
  node_gather_fused<<<(NNODES + 3) / 4, 256, 0, stream>>>(row_ptr, deg, eidx, edge_fea,
                                                          ss_e, out_edge, vbar_b);
  node_mlp_mfma<<<(NNODES + 31) / 32, 256, 0, stream>>>(node_b, vbar_b,
                                                        Wp_v1, bv1, Wp_v2, bv2, Wp_v3, bv3,
                                                        out_node, slots_v);
  stats_reduce<<<1, 256, 0, stream>>>(slots_v, NSLOT_V, 1.f / NNODES, gamma_v, beta_v, ss_v);
  node_finalize<<<(NNODES * DV) / 1024, 256, 0, stream>>>(node_fea, ss_v, out_node);
}